// Round 7
// baseline (41.204 us; speedup 1.0000x reference)
//
#include <hip/hip_runtime.h>
#include <math.h>

// PIT SI-SDR loss, B=32, C=3, T=96000, fp32 in, scalar fp32 out.
// Single kernel, fence-free "last block finishes" fusion with
// CONTENTION-FREE per-slot stores (no atomicAdd accumulation, no threadfence):
//   - each block reduces its 512-float4 tile to 21 Gram partials (fixed tree),
//   - wave 0 stores them to distinct slots with agent-scope relaxed atomic
//     stores (write to the device-coherent point, bypassing local L2),
//   - s_waitcnt vmcnt(0) drains those stores, then one counter atomicAdd,
//   - the last-arriving block reads all slots with agent-scope relaxed
//     atomic loads (bypasses its own, possibly poison-stale, L2), does the
//     column sums + 3x3 pair matrix + 6-perm max + -mean.
// Only the 4-byte counter needs re-zeroing each call (tiny memset node).
// All reductions are fixed-tree and identical to the verified R2 kernel.

#define T_LEN 96000
#define T4    24000          // T in float4
#define TILE4 512            // float4 per block tile
#define NT    47             // ceil(24000/512); last tile ragged (448/512)
#define B_SZ  32
#define NACC  21             // 3 se + 3 se2 + 3 sr + 3 sr2 + 9 dot
#define NPAIR (B_SZ * NACC)  // 672
#define NBLK  (B_SZ * NT)    // 1504
#define EPSF  1e-8f

__global__ __launch_bounds__(256) void pit_fused(const float* __restrict__ est,
                                                 const float* __restrict__ ref,
                                                 float* __restrict__ part,
                                                 unsigned int* __restrict__ counter,
                                                 float* __restrict__ out) {
    __shared__ float red[4][NACC];
    __shared__ int   isLast;

    const int b    = blockIdx.x / NT;
    const int tile = blockIdx.x - b * NT;

    const float4* e4 = reinterpret_cast<const float4*>(est) + (size_t)b * 3 * T4;
    const float4* r4 = reinterpret_cast<const float4*>(ref) + (size_t)b * 3 * T4;

    float se0=0.f, se1=0.f, se2=0.f;          // sum est
    float q0 =0.f, q1 =0.f, q2 =0.f;          // sum est^2
    float sr0=0.f, sr1=0.f, sr2=0.f;          // sum ref
    float w0 =0.f, w1 =0.f, w2 =0.f;          // sum ref^2
    float d00=0.f,d01=0.f,d02=0.f;            // dots est_i . ref_j
    float d10=0.f,d11=0.f,d12=0.f;
    float d20=0.f,d21=0.f,d22=0.f;

    const int base = tile * TILE4;

#define ACC(E0,E1,E2,R0,R1,R2) do {                                   \
        se0 += (E0); se1 += (E1); se2 += (E2);                        \
        q0  += (E0)*(E0); q1 += (E1)*(E1); q2 += (E2)*(E2);           \
        sr0 += (R0); sr1 += (R1); sr2 += (R2);                        \
        w0  += (R0)*(R0); w1 += (R1)*(R1); w2 += (R2)*(R2);           \
        d00 += (E0)*(R0); d01 += (E0)*(R1); d02 += (E0)*(R2);         \
        d10 += (E1)*(R0); d11 += (E1)*(R1); d12 += (E1)*(R2);         \
        d20 += (E2)*(R0); d21 += (E2)*(R1); d22 += (E2)*(R2);         \
    } while (0)

    // exactly R2's verified loop: 2 guarded groups of 256 float4
    #pragma unroll
    for (int k = 0; k < TILE4 / 256; ++k) {
        const int t4 = base + k * 256 + (int)threadIdx.x;
        if (t4 < T4) {
            const float4 a0 = e4[t4];
            const float4 a1 = e4[T4 + t4];
            const float4 a2 = e4[2 * T4 + t4];
            const float4 c0 = r4[t4];
            const float4 c1 = r4[T4 + t4];
            const float4 c2 = r4[2 * T4 + t4];
            ACC(a0.x, a1.x, a2.x, c0.x, c1.x, c2.x);
            ACC(a0.y, a1.y, a2.y, c0.y, c1.y, c2.y);
            ACC(a0.z, a1.z, a2.z, c0.z, c1.z, c2.z);
            ACC(a0.w, a1.w, a2.w, c0.w, c1.w, c2.w);
        }
    }
#undef ACC

    // 64-lane butterfly reduce all 21 accumulators.
#define RED1(X) X += __shfl_xor(X, off, 64)
    #pragma unroll
    for (int off = 32; off >= 1; off >>= 1) {
        RED1(se0); RED1(se1); RED1(se2);
        RED1(q0);  RED1(q1);  RED1(q2);
        RED1(sr0); RED1(sr1); RED1(sr2);
        RED1(w0);  RED1(w1);  RED1(w2);
        RED1(d00); RED1(d01); RED1(d02);
        RED1(d10); RED1(d11); RED1(d12);
        RED1(d20); RED1(d21); RED1(d22);
    }
#undef RED1

    const int lane = threadIdx.x & 63;
    const int wave = threadIdx.x >> 6;
    if (lane == 0) {
        red[wave][0]  = se0; red[wave][1]  = se1; red[wave][2]  = se2;
        red[wave][3]  = q0;  red[wave][4]  = q1;  red[wave][5]  = q2;
        red[wave][6]  = sr0; red[wave][7]  = sr1; red[wave][8]  = sr2;
        red[wave][9]  = w0;  red[wave][10] = w1;  red[wave][11] = w2;
        red[wave][12] = d00; red[wave][13] = d01; red[wave][14] = d02;
        red[wave][15] = d10; red[wave][16] = d11; red[wave][17] = d12;
        red[wave][18] = d20; red[wave][19] = d21; red[wave][20] = d22;
    }
    __syncthreads();

    // wave 0: per-slot device-coherent stores (no contention, no fence)
    // layout: part[tile*NPAIR + b*NACC + acc]
    if (threadIdx.x < NACC) {
        const float s = red[0][threadIdx.x] + red[1][threadIdx.x]
                      + red[2][threadIdx.x] + red[3][threadIdx.x];
        __hip_atomic_store(&part[(size_t)tile * NPAIR + b * NACC + threadIdx.x],
                           s, __ATOMIC_RELAXED, __HIP_MEMORY_SCOPE_AGENT);
    }
    // drain wave 0's stores to the coherent point before counting in
    asm volatile("s_waitcnt vmcnt(0)" ::: "memory");
    if (threadIdx.x == 0) {
        const unsigned int old = atomicAdd(counter, 1u);
        isLast = (old == (unsigned int)(NBLK - 1)) ? 1 : 0;
    }
    __syncthreads();
    if (!isLast) return;

    // ---- finish: last block only ----
    __shared__ float S[NPAIR];
    __shared__ float scores[B_SZ];

    for (int p = threadIdx.x; p < NPAIR; p += 256) {
        float s = 0.f;
        #pragma unroll
        for (int t = 0; t < NT; ++t)
            s += __hip_atomic_load(&part[(size_t)t * NPAIR + p],
                                   __ATOMIC_RELAXED, __HIP_MEMORY_SCOPE_AGENT);
        S[p] = s;
    }
    __syncthreads();

    if (threadIdx.x < B_SZ) {
        const float* v = &S[threadIdx.x * NACC];
        const float invT = 1.0f / (float)T_LEN;
        float se[3] = { v[0], v[1], v[2] };
        float q [3] = { v[3], v[4], v[5] };
        float sr[3] = { v[6], v[7], v[8] };
        float w [3] = { v[9], v[10], v[11] };

        float est_e[3], ref_e[3];
        #pragma unroll
        for (int i = 0; i < 3; ++i) est_e[i] = q[i] - se[i] * se[i] * invT;
        #pragma unroll
        for (int j = 0; j < 3; ++j) ref_e[j] = w[j] - sr[j] * sr[j] * invT;

        float pair[3][3];
        #pragma unroll
        for (int i = 0; i < 3; ++i) {
            #pragma unroll
            for (int j = 0; j < 3; ++j) {
                const float dc = v[12 + i * 3 + j] - se[i] * sr[j] * invT;
                const float te = dc * dc / (ref_e[j] + EPSF);
                const float ne = est_e[i] - te;
                pair[i][j] = 10.0f * log10f(te / (ne + EPSF) + EPSF);
            }
        }
        const float s0 = pair[0][0] + pair[1][1] + pair[2][2];
        const float s1 = pair[0][0] + pair[1][2] + pair[2][1];
        const float s2 = pair[0][1] + pair[1][0] + pair[2][2];
        const float s3 = pair[0][1] + pair[1][2] + pair[2][0];
        const float s4 = pair[0][2] + pair[1][0] + pair[2][1];
        const float s5 = pair[0][2] + pair[1][1] + pair[2][0];
        const float m = fmaxf(fmaxf(fmaxf(s0, s1), fmaxf(s2, s3)), fmaxf(s4, s5));
        scores[threadIdx.x] = m * (1.0f / 3.0f);
    }
    __syncthreads();

    if (threadIdx.x == 0) {
        float s = 0.f;
        #pragma unroll
        for (int bb = 0; bb < B_SZ; ++bb) s += scores[bb];
        out[0] = -s * (1.0f / (float)B_SZ);
    }
}

extern "C" void kernel_launch(void* const* d_in, const int* in_sizes, int n_in,
                              void* d_out, int out_size, void* d_ws, size_t ws_size,
                              hipStream_t stream) {
    const float* est = (const float*)d_in[0];
    const float* ref = (const float*)d_in[1];
    float* part = (float*)d_ws;                        // NT*NPAIR floats = 126 KB
    unsigned int* counter =
        (unsigned int*)((char*)d_ws + (size_t)NT * NPAIR * sizeof(float));
    float* outp = (float*)d_out;

    // re-zero ONLY the 4-byte counter each call (stream-ordered, capture-safe)
    hipMemsetAsync(counter, 0, sizeof(unsigned int), stream);
    pit_fused<<<dim3(NBLK), dim3(256), 0, stream>>>(est, ref, part, counter, outp);
}

// Round 8
// 22.520 us; speedup vs baseline: 1.8297x; 1.8297x over previous
//
#include <hip/hip_runtime.h>
#include <math.h>

// PIT SI-SDR loss, B=32, C=3, T=96000, fp32 in, scalar fp32 out.
// Two kernels (fusion handshakes measured >=10us on gfx950 - abandoned):
//  (1) pit_partial: 1024 blocks (exactly 4/CU), 750 float4 per block,
//      software-pipelined loads (12 in flight), Gram-statistics reduction.
//  (2) pit_finish: one block, coalesced 32-chunk column sums + 3x3 pair
//      matrix + 6-perm max + -mean.
// All reductions fixed-tree -> deterministic.

#define T_LEN  96000
#define T4     24000           // T in float4
#define B_SZ   32
#define NACC   21              // 3 se + 3 se2 + 3 sr + 3 sr2 + 9 dot
#define NPAIR  (B_SZ * NACC)   // 672
#define NCHUNK 32              // chunks per batch; 32*750 = 24000 exactly
#define CHUNK4 750             // float4 per chunk (no ragged remainder)
#define NBLK   (B_SZ * NCHUNK) // 1024 blocks = 4 blocks/CU on 256 CUs
#define EPSF   1e-8f

__global__ __launch_bounds__(256, 4) void pit_partial(const float* __restrict__ est,
                                                      const float* __restrict__ ref,
                                                      float* __restrict__ part) {
    const int b     = blockIdx.x >> 5;   // / NCHUNK
    const int chunk = blockIdx.x & 31;   // % NCHUNK

    const float4* e4 = reinterpret_cast<const float4*>(est) + (size_t)b * 3 * T4;
    const float4* r4 = reinterpret_cast<const float4*>(ref) + (size_t)b * 3 * T4;

    float se0=0.f, se1=0.f, se2=0.f;          // sum est
    float q0 =0.f, q1 =0.f, q2 =0.f;          // sum est^2
    float sr0=0.f, sr1=0.f, sr2=0.f;          // sum ref
    float w0 =0.f, w1 =0.f, w2 =0.f;          // sum ref^2
    float d00=0.f,d01=0.f,d02=0.f;            // dots est_i . ref_j
    float d10=0.f,d11=0.f,d12=0.f;
    float d20=0.f,d21=0.f,d22=0.f;

#define ACC(E0,E1,E2,R0,R1,R2) do {                                   \
        se0 += (E0); se1 += (E1); se2 += (E2);                        \
        q0  += (E0)*(E0); q1 += (E1)*(E1); q2 += (E2)*(E2);           \
        sr0 += (R0); sr1 += (R1); sr2 += (R2);                        \
        w0  += (R0)*(R0); w1 += (R1)*(R1); w2 += (R2)*(R2);           \
        d00 += (E0)*(R0); d01 += (E0)*(R1); d02 += (E0)*(R2);         \
        d10 += (E1)*(R0); d11 += (E1)*(R1); d12 += (E1)*(R2);         \
        d20 += (E2)*(R0); d21 += (E2)*(R1); d22 += (E2)*(R2);         \
    } while (0)

#define ACCG(A0,A1,A2,C0,C1,C2) do {                                  \
        ACC((A0).x, (A1).x, (A2).x, (C0).x, (C1).x, (C2).x);          \
        ACC((A0).y, (A1).y, (A2).y, (C0).y, (C1).y, (C2).y);          \
        ACC((A0).z, (A1).z, (A2).z, (C0).z, (C1).z, (C2).z);          \
        ACC((A0).w, (A1).w, (A2).w, (C0).w, (C1).w, (C2).w);          \
    } while (0)

    // 750 float4 per chunk: group0 = tid, group1 = tid+256,
    // group2 = tid+512 (active for tid < 238). No block reads out of range.
    const int t0 = chunk * CHUNK4 + (int)threadIdx.x;
    const int t1 = t0 + 256;
    const int t2 = t0 + 512;
    const bool g2 = (threadIdx.x < (CHUNK4 - 512));   // tid < 238

    // issue group 0 + group 1 loads (12 loads in flight)
    const float4 a00 = e4[t0];
    const float4 a01 = e4[T4 + t0];
    const float4 a02 = e4[2 * T4 + t0];
    const float4 c00 = r4[t0];
    const float4 c01 = r4[T4 + t0];
    const float4 c02 = r4[2 * T4 + t0];
    const float4 a10 = e4[t1];
    const float4 a11 = e4[T4 + t1];
    const float4 a12 = e4[2 * T4 + t1];
    const float4 c10 = r4[t1];
    const float4 c11 = r4[T4 + t1];
    const float4 c12 = r4[2 * T4 + t1];

    // consume group 0 while group 1 is still in flight
    ACCG(a00, a01, a02, c00, c01, c02);

    // issue group 2 (guarded) before consuming group 1
    float4 a20, a21, a22, c20, c21, c22;
    if (g2) {
        a20 = e4[t2];
        a21 = e4[T4 + t2];
        a22 = e4[2 * T4 + t2];
        c20 = r4[t2];
        c21 = r4[T4 + t2];
        c22 = r4[2 * T4 + t2];
    }

    ACCG(a10, a11, a12, c10, c11, c12);
    if (g2) {
        ACCG(a20, a21, a22, c20, c21, c22);
    }
#undef ACCG
#undef ACC

    // 64-lane butterfly reduce all 21 accumulators.
#define RED1(X) X += __shfl_xor(X, off, 64)
    #pragma unroll
    for (int off = 32; off >= 1; off >>= 1) {
        RED1(se0); RED1(se1); RED1(se2);
        RED1(q0);  RED1(q1);  RED1(q2);
        RED1(sr0); RED1(sr1); RED1(sr2);
        RED1(w0);  RED1(w1);  RED1(w2);
        RED1(d00); RED1(d01); RED1(d02);
        RED1(d10); RED1(d11); RED1(d12);
        RED1(d20); RED1(d21); RED1(d22);
    }
#undef RED1

    __shared__ float red[4][NACC];
    const int lane = threadIdx.x & 63;
    const int wave = threadIdx.x >> 6;
    if (lane == 0) {
        red[wave][0]  = se0; red[wave][1]  = se1; red[wave][2]  = se2;
        red[wave][3]  = q0;  red[wave][4]  = q1;  red[wave][5]  = q2;
        red[wave][6]  = sr0; red[wave][7]  = sr1; red[wave][8]  = sr2;
        red[wave][9]  = w0;  red[wave][10] = w1;  red[wave][11] = w2;
        red[wave][12] = d00; red[wave][13] = d01; red[wave][14] = d02;
        red[wave][15] = d10; red[wave][16] = d11; red[wave][17] = d12;
        red[wave][18] = d20; red[wave][19] = d21; red[wave][20] = d22;
    }
    __syncthreads();
    // layout: part[chunk*NPAIR + b*NACC + acc] -> coalesced column-sum in finish
    if (threadIdx.x < NACC) {
        const float s = red[0][threadIdx.x] + red[1][threadIdx.x]
                      + red[2][threadIdx.x] + red[3][threadIdx.x];
        part[(size_t)chunk * NPAIR + b * NACC + threadIdx.x] = s;
    }
}

// One block: reduce 32 chunks per (b,acc) column (coalesced), then per-batch
// pair matrix + permutation max, then -mean over batches.
__global__ __launch_bounds__(704) void pit_finish(const float* __restrict__ part,
                                                  float* __restrict__ out) {
    __shared__ float S[NPAIR];
    __shared__ float scores[B_SZ];
    const int p = threadIdx.x;

    if (p < NPAIR) {
        float s = 0.f;
        #pragma unroll
        for (int t = 0; t < NCHUNK; ++t) s += part[(size_t)t * NPAIR + p];
        S[p] = s;
    }
    __syncthreads();

    if (p < B_SZ) {
        const float* v = &S[p * NACC];
        const float invT = 1.0f / (float)T_LEN;
        float se[3] = { v[0], v[1], v[2] };
        float q [3] = { v[3], v[4], v[5] };
        float sr[3] = { v[6], v[7], v[8] };
        float w [3] = { v[9], v[10], v[11] };

        float est_e[3], ref_e[3];
        #pragma unroll
        for (int i = 0; i < 3; ++i) est_e[i] = q[i] - se[i] * se[i] * invT;
        #pragma unroll
        for (int j = 0; j < 3; ++j) ref_e[j] = w[j] - sr[j] * sr[j] * invT;

        float pair[3][3];
        #pragma unroll
        for (int i = 0; i < 3; ++i) {
            #pragma unroll
            for (int j = 0; j < 3; ++j) {
                const float dc = v[12 + i * 3 + j] - se[i] * sr[j] * invT;
                const float te = dc * dc / (ref_e[j] + EPSF);
                const float ne = est_e[i] - te;
                pair[i][j] = 10.0f * log10f(te / (ne + EPSF) + EPSF);
            }
        }
        const float s0 = pair[0][0] + pair[1][1] + pair[2][2];
        const float s1 = pair[0][0] + pair[1][2] + pair[2][1];
        const float s2 = pair[0][1] + pair[1][0] + pair[2][2];
        const float s3 = pair[0][1] + pair[1][2] + pair[2][0];
        const float s4 = pair[0][2] + pair[1][0] + pair[2][1];
        const float s5 = pair[0][2] + pair[1][1] + pair[2][0];
        const float m = fmaxf(fmaxf(fmaxf(s0, s1), fmaxf(s2, s3)), fmaxf(s4, s5));
        scores[p] = m * (1.0f / 3.0f);
    }
    __syncthreads();

    if (p == 0) {
        float s = 0.f;
        #pragma unroll
        for (int b = 0; b < B_SZ; ++b) s += scores[b];
        out[0] = -s * (1.0f / (float)B_SZ);
    }
}

extern "C" void kernel_launch(void* const* d_in, const int* in_sizes, int n_in,
                              void* d_out, int out_size, void* d_ws, size_t ws_size,
                              hipStream_t stream) {
    const float* est = (const float*)d_in[0];
    const float* ref = (const float*)d_in[1];
    float* part = (float*)d_ws;          // NCHUNK * NPAIR floats = 84 KB
    float* out  = (float*)d_out;

    pit_partial<<<dim3(NBLK), dim3(256), 0, stream>>>(est, ref, part);
    pit_finish <<<dim3(1),    dim3(704), 0, stream>>>(part, out);
}